// Round 1
// baseline (566.028 us; speedup 1.0000x reference)
//
#include <hip/hip_runtime.h>
#include <cstdint>
#include <cstddef>

// Problem constants: B=2, T=32, S=1024, D=512, H=8, hd=64, inner=512
// M = B*T*S = 65536 rows, K = 512 for both GEMMs.
#define KDIM 512

typedef __attribute__((ext_vector_type(8))) __bf16 bf16x8;
typedef __attribute__((ext_vector_type(8))) unsigned short ushort8;
typedef __attribute__((ext_vector_type(4))) float f32x4;
typedef unsigned short u16;

__device__ __forceinline__ float bf2f(u16 u) {
  union { unsigned u32; float f; } x; x.u32 = ((unsigned)u) << 16; return x.f;
}
__device__ __forceinline__ u16 f2bf(float f) {
  union { float f; unsigned u; } x; x.f = f;
  unsigned u = x.u;
  unsigned r = (u + 0x7fffu + ((u >> 16) & 1u)) >> 16;
  return (u16)r;
}

// ---------------- cast x (fp32 -> bf16), vectorized float4 ----------------
__global__ __launch_bounds__(256) void cast_x_kernel(const float* __restrict__ in,
                                                     u16* __restrict__ out, int n4) {
  int i = blockIdx.x * 256 + threadIdx.x;
  if (i >= n4) return;
  float4 v = ((const float4*)in)[i];
  ushort4 o;
  o.x = f2bf(v.x); o.y = f2bf(v.y); o.z = f2bf(v.z); o.w = f2bf(v.w);
  ((ushort4*)out)[i] = o;
}

// ---------------- transpose + cast W: in[R][C] fp32 -> out[C][R] bf16 ------
__global__ __launch_bounds__(256) void transpose_cast_kernel(const float* __restrict__ in,
                                                             u16* __restrict__ out,
                                                             int R, int C) {
  int o = blockIdx.x * 256 + threadIdx.x;
  if (o >= R * C) return;
  int r = o % R;
  int c = o / R;
  out[o] = f2bf(in[(size_t)r * C + c]);
}

// ---------------- GEMM: C[M][N] = A[M][K] * Bt[N][K]^T (bf16 in, OutT out) --
__device__ __forceinline__ void gload_lds16(const void* g, void* l) {
  __builtin_amdgcn_global_load_lds((__attribute__((address_space(1))) unsigned int*)g,
                                   (__attribute__((address_space(3))) unsigned int*)l,
                                   16, 0, 0);
}

template <typename OutT>
__global__ __launch_bounds__(256) void gemm_bt_kernel(const u16* __restrict__ A,
                                                      const u16* __restrict__ Bt,
                                                      OutT* __restrict__ C, int N) {
  __shared__ __attribute__((aligned(16))) u16 As[128 * 64];
  __shared__ __attribute__((aligned(16))) u16 Bs[128 * 64];
  const int tid = threadIdx.x;
  const int w = tid >> 6, lane = tid & 63;
  const int wr = w >> 1, wc = w & 1;
  const int m0 = blockIdx.y * 128;
  const int n0 = blockIdx.x * 128;
  const int lr = lane & 15, lk = lane >> 4;

  f32x4 acc[4][4] = {};

  for (int k0 = 0; k0 < KDIM; k0 += 64) {
    // stage A,B tiles (128x64 bf16 each) via global_load_lds width=16
#pragma unroll
    for (int j = 0; j < 4; ++j) {
      int chunk = w * 4 + j;                 // 16 chunks of 512 bf16 (8 rows)
      int row = chunk * 8 + (lane >> 3);
      int col = (lane & 7) * 8;
      gload_lds16(A + (size_t)(m0 + row) * KDIM + k0 + col, &As[chunk * 512]);
      gload_lds16(Bt + (size_t)(n0 + row) * KDIM + k0 + col, &Bs[chunk * 512]);
    }
    __syncthreads();
#pragma unroll
    for (int kk = 0; kk < 64; kk += 32) {
      bf16x8 af[4], bfr[4];
#pragma unroll
      for (int m = 0; m < 4; ++m)
        af[m] = *(const bf16x8*)&As[(wr * 64 + m * 16 + lr) * 64 + kk + lk * 8];
#pragma unroll
      for (int n = 0; n < 4; ++n)
        bfr[n] = *(const bf16x8*)&Bs[(wc * 64 + n * 16 + lr) * 64 + kk + lk * 8];
#pragma unroll
      for (int m = 0; m < 4; ++m)
#pragma unroll
        for (int n = 0; n < 4; ++n)
          acc[m][n] = __builtin_amdgcn_mfma_f32_16x16x32_bf16(af[m], bfr[n], acc[m][n], 0, 0, 0);
    }
    __syncthreads();
  }

  // epilogue: C/D layout col = lane&15, row = (lane>>4)*4 + r
#pragma unroll
  for (int m = 0; m < 4; ++m) {
    int rowb = m0 + wr * 64 + m * 16 + lk * 4;
#pragma unroll
    for (int n = 0; n < 4; ++n) {
      int colg = n0 + wc * 64 + n * 16 + lr;
#pragma unroll
      for (int r = 0; r < 4; ++r) {
        size_t idx = (size_t)(rowb + r) * N + colg;
        float v = acc[m][n][r];
        if constexpr (sizeof(OutT) == 2) {
          C[idx] = (OutT)f2bf(v);
        } else {
          C[idx] = v;
        }
      }
    }
  }
}

// ---------------- temporal attention over T=32, per (b,s) block ------------
// qkv layout: row = ((b*32+t)*1024+s), col = c*512 + h*64 + d, ld=1536, bf16
// out: row = ((b*32+q)*1024+s), col = h*64 + d, ld=512, bf16
__global__ __launch_bounds__(256) void attn_kernel(const u16* __restrict__ qkv,
                                                   u16* __restrict__ out) {
  const int b = blockIdx.x >> 10;
  const int s = blockIdx.x & 1023;
  // padded chunks: [t][h][72] (chunk stride 144B = 16B-aligned, bank-spread)
  __shared__ __attribute__((aligned(16))) u16 Ks[32][8][72];
  __shared__ __attribute__((aligned(16))) u16 Vs[32][8][72];
  const int tid = threadIdx.x;

  // stage K and V (32 x 512 bf16 each) cooperatively, 16B per load
#pragma unroll
  for (int it = 0; it < 8; ++it) {
    int i = it * 256 + tid;       // chunk of 8 bf16, 0..2047
    int flat = i * 8;
    int row = flat >> 9;
    int off = flat & 511;
    int hh = off >> 6, dd = off & 63;
    const u16* gk = qkv + ((size_t)((b * 32 + row) * 1024 + s)) * 1536 + 512 + off;
    ushort8 kv = *(const ushort8*)gk;
    ushort8 vv = *(const ushort8*)(gk + 512);
    *(ushort8*)&Ks[row][hh][dd] = kv;
    *(ushort8*)&Vs[row][hh][dd] = vv;
  }
  __syncthreads();

  const int q = tid >> 3, h = tid & 7;
  const u16* gq = qkv + ((size_t)((b * 32 + q) * 1024 + s)) * 1536 + h * 64;

  float qr[64];
#pragma unroll
  for (int j = 0; j < 64; j += 8) {
    ushort8 v = *(const ushort8*)(gq + j);
#pragma unroll
    for (int u = 0; u < 8; ++u) qr[j + u] = bf2f(v[u]);
  }

  float sc[32];
#pragma unroll
  for (int k = 0; k < 32; ++k) {
    float d = 0.f;
#pragma unroll
    for (int j = 0; j < 64; j += 8) {
      ushort8 kv = *(const ushort8*)&Ks[k][h][j];
#pragma unroll
      for (int u = 0; u < 8; ++u) d += qr[j + u] * bf2f(kv[u]);
    }
    sc[k] = d * 0.125f;  // hd^-0.5
  }

  float mx = -1e30f;
#pragma unroll
  for (int k = 0; k < 32; ++k)
    if (k <= q) mx = fmaxf(mx, sc[k]);
  float sum = 0.f;
#pragma unroll
  for (int k = 0; k < 32; ++k) {
    float p = (k <= q) ? __expf(sc[k] - mx) : 0.f;
    sc[k] = p;
    sum += p;
  }
  float inv = 1.f / sum;

  float acc[64];
#pragma unroll
  for (int j = 0; j < 64; ++j) acc[j] = 0.f;
#pragma unroll
  for (int k = 0; k < 32; ++k) {
    float p = sc[k] * inv;
#pragma unroll
    for (int j = 0; j < 64; j += 8) {
      ushort8 vv = *(const ushort8*)&Vs[k][h][j];
#pragma unroll
      for (int u = 0; u < 8; ++u) acc[j + u] += p * bf2f(vv[u]);
    }
  }

  u16* go = out + ((size_t)((b * 32 + q) * 1024 + s)) * 512 + h * 64;
#pragma unroll
  for (int j = 0; j < 64; j += 8) {
    ushort8 o;
#pragma unroll
    for (int u = 0; u < 8; ++u) o[u] = f2bf(acc[j + u]);
    *(ushort8*)(go + j) = o;
  }
}

// ---------------------------------------------------------------------------
extern "C" void kernel_launch(void* const* d_in, const int* in_sizes, int n_in,
                              void* d_out, int out_size, void* d_ws, size_t ws_size,
                              hipStream_t stream) {
  const float* x = (const float*)d_in[0];     // [2,32,1024,512] fp32
  const float* Wqkv = (const float*)d_in[1];  // [512,1536] fp32
  const float* Wout = (const float*)d_in[2];  // [512,512] fp32
  float* outp = (float*)d_out;                // [2,32,1024,512] fp32

  char* ws = (char*)d_ws;
  // layout: [0,64MiB) x_bf16 (later aliased as attn_out), [64MiB,256MiB) qkv,
  //         [256MiB, +1.5MiB) Wqkv^T, then +0.5MiB Wout^T   (total ~258 MiB)
  u16* x_bf = (u16*)(ws);
  u16* qkv_bf = (u16*)(ws + (size_t)67108864);
  u16* wqkv_t = (u16*)(ws + (size_t)268435456);
  u16* wout_t = (u16*)(ws + (size_t)270008320);
  u16* attn_o = x_bf;  // alias: x_bf16 dead after GEMM1

  // 1) casts
  cast_x_kernel<<<32768, 256, 0, stream>>>(x, x_bf, 8388608);           // 33.5M/4
  transpose_cast_kernel<<<3072, 256, 0, stream>>>(Wqkv, wqkv_t, 512, 1536);
  transpose_cast_kernel<<<1024, 256, 0, stream>>>(Wout, wout_t, 512, 512);

  // 2) QKV GEMM: [65536,512] x [512,1536] -> [65536,1536] bf16
  dim3 g1(12, 512);
  gemm_bt_kernel<u16><<<g1, 256, 0, stream>>>(x_bf, wqkv_t, qkv_bf, 1536);

  // 3) temporal attention, one block per (b,s)
  attn_kernel<<<2048, 256, 0, stream>>>(qkv_bf, attn_o);

  // 4) out projection: [65536,512] x [512,512] -> [65536,512] fp32
  dim3 g2(4, 512);
  gemm_bt_kernel<float><<<g2, 256, 0, stream>>>(attn_o, wout_t, outp, 512);
}

// Round 2
// 459.560 us; speedup vs baseline: 1.2317x; 1.2317x over previous
//
#include <hip/hip_runtime.h>
#include <cstdint>
#include <cstddef>

// Problem constants: B=2, T=32, S=1024, D=512, H=8, hd=64, inner=512
// M = B*T*S = 65536 rows, K = 512 for both GEMMs.
#define KDIM 512

typedef __attribute__((ext_vector_type(8))) __bf16 bf16x8;
typedef __attribute__((ext_vector_type(8))) unsigned short ushort8;
typedef __attribute__((ext_vector_type(4))) float f32x4;
typedef unsigned short u16;

__device__ __forceinline__ float bf2f(u16 u) {
  union { unsigned u32; float f; } x; x.u32 = ((unsigned)u) << 16; return x.f;
}
__device__ __forceinline__ u16 f2bf(float f) {
  union { float f; unsigned u; } x; x.f = f;
  unsigned u = x.u;
  unsigned r = (u + 0x7fffu + ((u >> 16) & 1u)) >> 16;
  return (u16)r;
}

// ---------------- cast x (fp32 -> bf16), vectorized float4 ----------------
__global__ __launch_bounds__(256) void cast_x_kernel(const float* __restrict__ in,
                                                     u16* __restrict__ out, int n4) {
  int i = blockIdx.x * 256 + threadIdx.x;
  if (i >= n4) return;
  float4 v = ((const float4*)in)[i];
  ushort4 o;
  o.x = f2bf(v.x); o.y = f2bf(v.y); o.z = f2bf(v.z); o.w = f2bf(v.w);
  ((ushort4*)out)[i] = o;
}

// ---------------- transpose + cast W: in[R][C] fp32 -> out[C][R] bf16 ------
__global__ __launch_bounds__(256) void transpose_cast_kernel(const float* __restrict__ in,
                                                             u16* __restrict__ out,
                                                             int R, int C) {
  int o = blockIdx.x * 256 + threadIdx.x;
  if (o >= R * C) return;
  int r = o % R;
  int c = o / R;
  out[o] = f2bf(in[(size_t)r * C + c]);
}

// ---------------- GEMM: C[M][N] = A[M][K] * Bt[N][K]^T (bf16 in, OutT out) --
__device__ __forceinline__ void gload_lds16(const void* g, void* l) {
  __builtin_amdgcn_global_load_lds((__attribute__((address_space(1))) unsigned int*)g,
                                   (__attribute__((address_space(3))) unsigned int*)l,
                                   16, 0, 0);
}

template <typename OutT>
__global__ __launch_bounds__(256) void gemm_bt_kernel(const u16* __restrict__ A,
                                                      const u16* __restrict__ Bt,
                                                      OutT* __restrict__ C, int N) {
  __shared__ __attribute__((aligned(16))) u16 As[128 * 64];
  __shared__ __attribute__((aligned(16))) u16 Bs[128 * 64];
  const int tid = threadIdx.x;
  const int w = tid >> 6, lane = tid & 63;
  const int wr = w >> 1, wc = w & 1;
  const int m0 = blockIdx.y * 128;
  const int n0 = blockIdx.x * 128;
  const int lr = lane & 15, lk = lane >> 4;

  f32x4 acc[4][4] = {};

  for (int k0 = 0; k0 < KDIM; k0 += 64) {
    // stage A,B tiles (128x64 bf16 each) via global_load_lds width=16
#pragma unroll
    for (int j = 0; j < 4; ++j) {
      int chunk = w * 4 + j;                 // 16 chunks of 512 bf16 (8 rows)
      int row = chunk * 8 + (lane >> 3);
      int col = (lane & 7) * 8;
      gload_lds16(A + (size_t)(m0 + row) * KDIM + k0 + col, &As[chunk * 512]);
      gload_lds16(Bt + (size_t)(n0 + row) * KDIM + k0 + col, &Bs[chunk * 512]);
    }
    __syncthreads();
#pragma unroll
    for (int kk = 0; kk < 64; kk += 32) {
      bf16x8 af[4], bfr[4];
#pragma unroll
      for (int m = 0; m < 4; ++m)
        af[m] = *(const bf16x8*)&As[(wr * 64 + m * 16 + lr) * 64 + kk + lk * 8];
#pragma unroll
      for (int n = 0; n < 4; ++n)
        bfr[n] = *(const bf16x8*)&Bs[(wc * 64 + n * 16 + lr) * 64 + kk + lk * 8];
#pragma unroll
      for (int m = 0; m < 4; ++m)
#pragma unroll
        for (int n = 0; n < 4; ++n)
          acc[m][n] = __builtin_amdgcn_mfma_f32_16x16x32_bf16(af[m], bfr[n], acc[m][n], 0, 0, 0);
    }
    __syncthreads();
  }

  // epilogue: C/D layout col = lane&15, row = (lane>>4)*4 + r
#pragma unroll
  for (int m = 0; m < 4; ++m) {
    int rowb = m0 + wr * 64 + m * 16 + lk * 4;
#pragma unroll
    for (int n = 0; n < 4; ++n) {
      int colg = n0 + wc * 64 + n * 16 + lr;
#pragma unroll
      for (int r = 0; r < 4; ++r) {
        size_t idx = (size_t)(rowb + r) * N + colg;
        float v = acc[m][n][r];
        if constexpr (sizeof(OutT) == 2) {
          C[idx] = (OutT)f2bf(v);
        } else {
          C[idx] = v;
        }
      }
    }
  }
}

// ---------------- temporal attention over T=32, per (b,s) block ------------
// qkv layout: row = ((b*32+t)*1024+s), col = c*512 + h*64 + d, ld=1536, bf16
// out: row = ((b*32+q)*1024+s), col = h*64 + d, ld=512, bf16
// 512 threads: thread = (q, h, e) with e = d-half. Peak live regs ~64 floats
// (qr[32]+sc[32] during QK; sc[32]+acc[32] during PV) -> no scratch spill.
__global__ __launch_bounds__(512) void attn_kernel(const u16* __restrict__ qkv,
                                                   u16* __restrict__ out) {
  const int b = blockIdx.x >> 10;
  const int s = blockIdx.x & 1023;
  // padded chunks: [t][h][72] (chunk stride 144B = 16B-aligned, bank-spread)
  __shared__ __attribute__((aligned(16))) u16 Ks[32][8][72];
  __shared__ __attribute__((aligned(16))) u16 Vs[32][8][72];
  const int tid = threadIdx.x;

  // stage K and V (32 x 512 bf16 each) cooperatively, 16B per load
#pragma unroll
  for (int it = 0; it < 4; ++it) {
    int i = it * 512 + tid;       // chunk of 8 bf16, 0..2047
    int flat = i * 8;
    int row = flat >> 9;
    int off = flat & 511;
    int hh = off >> 6, dd = off & 63;
    const u16* gk = qkv + ((size_t)((b * 32 + row) * 1024 + s)) * 1536 + 512 + off;
    ushort8 kv = *(const ushort8*)gk;
    ushort8 vv = *(const ushort8*)(gk + 512);
    *(ushort8*)&Ks[row][hh][dd] = kv;
    *(ushort8*)&Vs[row][hh][dd] = vv;
  }
  __syncthreads();

  const int q = tid >> 4;
  const int h = (tid >> 1) & 7;
  const int e = tid & 1;
  const int d0 = e * 32;

  // load this thread's Q d-half (32 floats)
  const u16* gq = qkv + ((size_t)((b * 32 + q) * 1024 + s)) * 1536 + h * 64 + d0;
  float qr[32];
#pragma unroll
  for (int j = 0; j < 32; j += 8) {
    ushort8 v = *(const ushort8*)(gq + j);
#pragma unroll
    for (int u = 0; u < 8; ++u) qr[j + u] = bf2f(v[u]);
  }

  // partial scores over this d-half
  float sc[32];
#pragma unroll
  for (int k = 0; k < 32; ++k) {
    float d = 0.f;
#pragma unroll
    for (int j = 0; j < 32; j += 8) {
      ushort8 kv = *(const ushort8*)&Ks[k][h][d0 + j];
#pragma unroll
      for (int u = 0; u < 8; ++u) d += qr[j + u] * bf2f(kv[u]);
    }
    sc[k] = d;
  }
  // combine halves: e-partner is adjacent lane (tid bit 0 = lane bit 0)
#pragma unroll
  for (int k = 0; k < 32; ++k) sc[k] += __shfl_xor(sc[k], 1);

  // softmax over k<=q (scale = hd^-0.5 = 0.125)
  float mx = -1e30f;
#pragma unroll
  for (int k = 0; k < 32; ++k)
    if (k <= q) mx = fmaxf(mx, sc[k] * 0.125f);
  float sum = 0.f;
#pragma unroll
  for (int k = 0; k < 32; ++k) {
    float p = (k <= q) ? __expf(sc[k] * 0.125f - mx) : 0.f;
    sc[k] = p;
    sum += p;
  }
  float inv = 1.f / sum;

  // PV over this d-half
  float acc[32];
#pragma unroll
  for (int j = 0; j < 32; ++j) acc[j] = 0.f;
#pragma unroll
  for (int k = 0; k < 32; ++k) {
    float p = sc[k] * inv;
#pragma unroll
    for (int j = 0; j < 32; j += 8) {
      ushort8 vv = *(const ushort8*)&Vs[k][h][d0 + j];
#pragma unroll
      for (int u = 0; u < 8; ++u) acc[j + u] += p * bf2f(vv[u]);
    }
  }

  u16* go = out + ((size_t)((b * 32 + q) * 1024 + s)) * 512 + h * 64 + d0;
#pragma unroll
  for (int j = 0; j < 32; j += 8) {
    ushort8 o;
#pragma unroll
    for (int u = 0; u < 8; ++u) o[u] = f2bf(acc[j + u]);
    *(ushort8*)(go + j) = o;
  }
}

// ---------------------------------------------------------------------------
extern "C" void kernel_launch(void* const* d_in, const int* in_sizes, int n_in,
                              void* d_out, int out_size, void* d_ws, size_t ws_size,
                              hipStream_t stream) {
  const float* x = (const float*)d_in[0];     // [2,32,1024,512] fp32
  const float* Wqkv = (const float*)d_in[1];  // [512,1536] fp32
  const float* Wout = (const float*)d_in[2];  // [512,512] fp32
  float* outp = (float*)d_out;                // [2,32,1024,512] fp32

  char* ws = (char*)d_ws;
  // layout: [0,64MiB) x_bf16 (later aliased as attn_out), [64MiB,256MiB) qkv,
  //         [256MiB, +1.5MiB) Wqkv^T, then +0.5MiB Wout^T   (total ~258 MiB)
  u16* x_bf = (u16*)(ws);
  u16* qkv_bf = (u16*)(ws + (size_t)67108864);
  u16* wqkv_t = (u16*)(ws + (size_t)268435456);
  u16* wout_t = (u16*)(ws + (size_t)270008320);
  u16* attn_o = x_bf;  // alias: x_bf16 dead after GEMM1

  // 1) casts
  cast_x_kernel<<<32768, 256, 0, stream>>>(x, x_bf, 8388608);           // 33.5M/4
  transpose_cast_kernel<<<3072, 256, 0, stream>>>(Wqkv, wqkv_t, 512, 1536);
  transpose_cast_kernel<<<1024, 256, 0, stream>>>(Wout, wout_t, 512, 512);

  // 2) QKV GEMM: [65536,512] x [512,1536] -> [65536,1536] bf16
  dim3 g1(12, 512);
  gemm_bt_kernel<u16><<<g1, 256, 0, stream>>>(x_bf, wqkv_t, qkv_bf, 1536);

  // 3) temporal attention, one block per (b,s), 512 threads
  attn_kernel<<<2048, 512, 0, stream>>>(qkv_bf, attn_o);

  // 4) out projection: [65536,512] x [512,512] -> [65536,512] fp32
  dim3 g2(4, 512);
  gemm_bt_kernel<float><<<g2, 256, 0, stream>>>(attn_o, wout_t, outp, 512);
}

// Round 3
// 347.297 us; speedup vs baseline: 1.6298x; 1.3232x over previous
//
#include <hip/hip_runtime.h>
#include <cstdint>
#include <cstddef>

// Problem constants: B=2, T=32, S=1024, D=512, H=8, hd=64, inner=512
#define KDIM 512

typedef __attribute__((ext_vector_type(8))) __bf16 bf16x8;
typedef __attribute__((ext_vector_type(8))) unsigned short ushort8;
typedef __attribute__((ext_vector_type(4))) float f32x4;
typedef unsigned short u16;

__device__ __forceinline__ float bf2f(u16 u) {
  union { unsigned u32; float f; } x; x.u32 = ((unsigned)u) << 16; return x.f;
}
__device__ __forceinline__ u16 f2bf(float f) {
  union { float f; unsigned u; } x; x.f = f;
  unsigned u = x.u;
  unsigned r = (u + 0x7fffu + ((u >> 16) & 1u)) >> 16;
  return (u16)r;
}

// ---------------- cast x (fp32 -> bf16), vectorized float4 ----------------
__global__ __launch_bounds__(256) void cast_x_kernel(const float* __restrict__ in,
                                                     u16* __restrict__ out, int n4) {
  int i = blockIdx.x * 256 + threadIdx.x;
  if (i >= n4) return;
  float4 v = ((const float4*)in)[i];
  ushort4 o;
  o.x = f2bf(v.x); o.y = f2bf(v.y); o.z = f2bf(v.z); o.w = f2bf(v.w);
  ((ushort4*)out)[i] = o;
}

// ---------------- transpose + cast W: in[R][C] fp32 -> out[C][R] bf16 ------
__global__ __launch_bounds__(256) void transpose_cast_kernel(const float* __restrict__ in,
                                                             u16* __restrict__ out,
                                                             int R, int C) {
  int o = blockIdx.x * 256 + threadIdx.x;
  if (o >= R * C) return;
  int r = o % R;
  int c = o / R;
  out[o] = f2bf(in[(size_t)r * C + c]);
}

// ---------------- GEMM: C[M][N] = A[M][K] * Bt[N][K]^T (bf16 in, OutT out) --
__device__ __forceinline__ void gload_lds16(const void* g, void* l) {
  __builtin_amdgcn_global_load_lds((__attribute__((address_space(1))) unsigned int*)g,
                                   (__attribute__((address_space(3))) unsigned int*)l,
                                   16, 0, 0);
}

template <typename OutT>
__global__ __launch_bounds__(256) void gemm_bt_kernel(const u16* __restrict__ A,
                                                      const u16* __restrict__ Bt,
                                                      OutT* __restrict__ C, int N) {
  __shared__ __attribute__((aligned(16))) u16 As[128 * 64];
  __shared__ __attribute__((aligned(16))) u16 Bs[128 * 64];
  const int tid = threadIdx.x;
  const int w = tid >> 6, lane = tid & 63;
  const int wr = w >> 1, wc = w & 1;
  const int m0 = blockIdx.y * 128;
  const int n0 = blockIdx.x * 128;
  const int lr = lane & 15, lk = lane >> 4;

  f32x4 acc[4][4] = {};

  for (int k0 = 0; k0 < KDIM; k0 += 64) {
#pragma unroll
    for (int j = 0; j < 4; ++j) {
      int chunk = w * 4 + j;
      int row = chunk * 8 + (lane >> 3);
      int col = (lane & 7) * 8;
      gload_lds16(A + (size_t)(m0 + row) * KDIM + k0 + col, &As[chunk * 512]);
      gload_lds16(Bt + (size_t)(n0 + row) * KDIM + k0 + col, &Bs[chunk * 512]);
    }
    __syncthreads();
#pragma unroll
    for (int kk = 0; kk < 64; kk += 32) {
      bf16x8 af[4], bfr[4];
#pragma unroll
      for (int m = 0; m < 4; ++m)
        af[m] = *(const bf16x8*)&As[(wr * 64 + m * 16 + lr) * 64 + kk + lk * 8];
#pragma unroll
      for (int n = 0; n < 4; ++n)
        bfr[n] = *(const bf16x8*)&Bs[(wc * 64 + n * 16 + lr) * 64 + kk + lk * 8];
#pragma unroll
      for (int m = 0; m < 4; ++m)
#pragma unroll
        for (int n = 0; n < 4; ++n)
          acc[m][n] = __builtin_amdgcn_mfma_f32_16x16x32_bf16(af[m], bfr[n], acc[m][n], 0, 0, 0);
    }
    __syncthreads();
  }

#pragma unroll
  for (int m = 0; m < 4; ++m) {
    int rowb = m0 + wr * 64 + m * 16 + lk * 4;
#pragma unroll
    for (int n = 0; n < 4; ++n) {
      int colg = n0 + wc * 64 + n * 16 + lr;
#pragma unroll
      for (int r = 0; r < 4; ++r) {
        size_t idx = (size_t)(rowb + r) * N + colg;
        float v = acc[m][n][r];
        if constexpr (sizeof(OutT) == 2) {
          C[idx] = (OutT)f2bf(v);
        } else {
          C[idx] = v;
        }
      }
    }
  }
}

// ---------------- MFMA temporal attention ----------------------------------
// Block = (b, s, head-group of 4). 256 threads = 4 waves, wave = one head.
// Per head: S^T = mfma(A=K, B=Q)  (swapped -> softmax k-reduce is in-lane+2 shfl)
//           out = mfma(A=P, B=V^T)
// LDS per head: Ks[32k][64d] 4KB (XOR-swizzled, filled by global_load_lds with
// pre-swizzled SOURCE addresses), Vt[64d][32k] 4KB (reg-staged transpose,
// XOR-swizzled), Ps[32q][32k] 2KB (XOR-swizzled). 40KB/block -> 4 blocks/CU.
__global__ __launch_bounds__(256, 4) void attn_mfma_kernel(const u16* __restrict__ qkv,
                                                           u16* __restrict__ out) {
  const int bs = blockIdx.x >> 1;
  const int hg = blockIdx.x & 1;
  const int b = bs >> 10, s = bs & 1023;
  __shared__ __attribute__((aligned(16))) u16 Ks[4][2048];
  __shared__ __attribute__((aligned(16))) u16 Vt[4][2048];
  __shared__ __attribute__((aligned(16))) u16 Ps[4][1024];

  const int tid = threadIdx.x;
  const int wv = tid >> 6;            // wave in block = head within group
  const int h = hg * 4 + wv;
  const int l = tid & 63;
  const int g = l >> 4, i = l & 15;

  const size_t tstride = (size_t)1024 * 1536;                 // u16 per t-step
  const size_t base = ((size_t)(b * 32) * 1024 + s) * 1536;   // row (b, t=0, s)

  // ---- issue K staging: global_load_lds, source block pre-swizzled --------
  {
    const int krow = l >> 3;                 // row within group of 8
    const int dbs = (l & 7) ^ krow;          // source 16B-block (swizzle)
#pragma unroll
    for (int j = 0; j < 4; ++j) {
      int k = j * 8 + krow;
      const u16* src = qkv + base + (size_t)k * tstride + 512 + h * 64 + dbs * 8;
      gload_lds16(src, &Ks[wv][j * 512]);
    }
  }

  // ---- issue V loads (reg-staged) -----------------------------------------
  const int vk = l & 31;
  ushort8 vv[4];
#pragma unroll
  for (int j = 0; j < 4; ++j) {
    int c = (l >> 5) + 2 * j;                // d-chunk 0..7
    vv[j] = *(const ushort8*)(qkv + base + (size_t)vk * tstride + 1024 + h * 64 + c * 8);
  }

  // ---- issue Q B-fragment loads directly from global ----------------------
  bf16x8 bq[2][2];
#pragma unroll
  for (int n = 0; n < 2; ++n)
#pragma unroll
    for (int ks = 0; ks < 2; ++ks)
      bq[n][ks] = *(const bf16x8*)(qkv + base + (size_t)(n * 16 + i) * tstride + h * 64 + ks * 32 + g * 8);

  // ---- write V transposed into Vt (XOR-swizzled) --------------------------
#pragma unroll
  for (int j = 0; j < 4; ++j) {
    int c = (l >> 5) + 2 * j;
#pragma unroll
    for (int u = 0; u < 8; ++u) {
      int d = c * 8 + u;
      int pos = (vk >> 3) ^ (d & 3);
      Vt[wv][d * 32 + pos * 8 + (vk & 7)] = vv[j][u];
    }
  }

  // drain global_load_lds (K) before reading Ks; Q/V loads resolved by deps
  asm volatile("s_waitcnt vmcnt(0)" ::: "memory");

  // ---- QK^T (swapped): S^T[k][q], 8 MFMAs ---------------------------------
  f32x4 sc[2][2] = {};
#pragma unroll
  for (int m = 0; m < 2; ++m)
#pragma unroll
    for (int ks = 0; ks < 2; ++ks) {
      int k = m * 16 + i;
      int pos = (ks * 4 + g) ^ (k & 7);
      bf16x8 ak = *(const bf16x8*)&Ks[wv][k * 64 + pos * 8];
      sc[m][0] = __builtin_amdgcn_mfma_f32_16x16x32_bf16(ak, bq[0][ks], sc[m][0], 0, 0, 0);
      sc[m][1] = __builtin_amdgcn_mfma_f32_16x16x32_bf16(ak, bq[1][ks], sc[m][1], 0, 0, 0);
    }

  // ---- softmax over k (per q-column): in-lane 8 vals + shfl_xor 16,32 -----
  // lane holds S^T[k = m*16+g*4+r][q = n*16+i]
  float p[2][2][4];
#pragma unroll
  for (int n = 0; n < 2; ++n) {
    int q = n * 16 + i;
    float m0 = -1e30f;
#pragma unroll
    for (int m = 0; m < 2; ++m)
#pragma unroll
      for (int r = 0; r < 4; ++r) {
        int k = m * 16 + g * 4 + r;
        float v = (k <= q) ? sc[m][n][r] * 0.125f : -1e30f;
        p[m][n][r] = v;
        m0 = fmaxf(m0, v);
      }
    m0 = fmaxf(m0, __shfl_xor(m0, 16));
    m0 = fmaxf(m0, __shfl_xor(m0, 32));
    float s0 = 0.f;
#pragma unroll
    for (int m = 0; m < 2; ++m)
#pragma unroll
      for (int r = 0; r < 4; ++r) {
        float e = __expf(p[m][n][r] - m0);
        p[m][n][r] = e;
        s0 += e;
      }
    s0 += __shfl_xor(s0, 16);
    s0 += __shfl_xor(s0, 32);
    float inv = 1.f / s0;
#pragma unroll
    for (int m = 0; m < 2; ++m)
#pragma unroll
      for (int r = 0; r < 4; ++r) p[m][n][r] *= inv;
  }

  // ---- pack P^T -> Ps[q][k] bf16 (b64 writes, XOR-swizzled) ---------------
#pragma unroll
  for (int m = 0; m < 2; ++m)
#pragma unroll
    for (int n = 0; n < 2; ++n) {
      int q = n * 16 + i;
      int kb = m * 2 + (g >> 1);           // (m*16+g*4)>>3
      int pos = kb ^ (q & 3);
      uint2 wo;
      wo.x = (unsigned)f2bf(p[m][n][0]) | ((unsigned)f2bf(p[m][n][1]) << 16);
      wo.y = (unsigned)f2bf(p[m][n][2]) | ((unsigned)f2bf(p[m][n][3]) << 16);
      *(uint2*)&Ps[wv][q * 32 + pos * 8 + (g & 1) * 4] = wo;
    }

  // P writes + Vt writes must land before PV reads (same wave only)
  asm volatile("s_waitcnt lgkmcnt(0)" ::: "memory");

  // ---- PV: out[q][d] = P[q][k] * Vt[d][k]^T, 8 MFMAs ----------------------
  bf16x8 bv[4];
#pragma unroll
  for (int np = 0; np < 4; ++np) {
    int d = np * 16 + i;
    int pos = g ^ (d & 3);
    bv[np] = *(const bf16x8*)&Vt[wv][d * 32 + pos * 8];
  }
  f32x4 o[2][4] = {};
#pragma unroll
  for (int mp = 0; mp < 2; ++mp) {
    int q = mp * 16 + i;
    int pos = g ^ (q & 3);
    bf16x8 ap = *(const bf16x8*)&Ps[wv][q * 32 + pos * 8];
#pragma unroll
    for (int np = 0; np < 4; ++np)
      o[mp][np] = __builtin_amdgcn_mfma_f32_16x16x32_bf16(ap, bv[np], o[mp][np], 0, 0, 0);
  }

  // ---- write out bf16: row q = mp*16+g*4+r, col d = np*16+i ---------------
#pragma unroll
  for (int mp = 0; mp < 2; ++mp)
#pragma unroll
    for (int r = 0; r < 4; ++r) {
      int q = mp * 16 + g * 4 + r;
      u16* dst = out + ((size_t)((b * 32 + q) * 1024 + s)) * 512 + h * 64;
#pragma unroll
      for (int np = 0; np < 4; ++np)
        dst[np * 16 + i] = f2bf(o[mp][np][r]);
    }
}

// ---------------------------------------------------------------------------
extern "C" void kernel_launch(void* const* d_in, const int* in_sizes, int n_in,
                              void* d_out, int out_size, void* d_ws, size_t ws_size,
                              hipStream_t stream) {
  const float* x = (const float*)d_in[0];     // [2,32,1024,512] fp32
  const float* Wqkv = (const float*)d_in[1];  // [512,1536] fp32
  const float* Wout = (const float*)d_in[2];  // [512,512] fp32
  float* outp = (float*)d_out;                // [2,32,1024,512] fp32

  char* ws = (char*)d_ws;
  u16* x_bf = (u16*)(ws);
  u16* qkv_bf = (u16*)(ws + (size_t)67108864);
  u16* wqkv_t = (u16*)(ws + (size_t)268435456);
  u16* wout_t = (u16*)(ws + (size_t)270008320);
  u16* attn_o = x_bf;  // alias: x_bf16 dead after GEMM1

  // 1) casts
  cast_x_kernel<<<32768, 256, 0, stream>>>(x, x_bf, 8388608);
  transpose_cast_kernel<<<3072, 256, 0, stream>>>(Wqkv, wqkv_t, 512, 1536);
  transpose_cast_kernel<<<1024, 256, 0, stream>>>(Wout, wout_t, 512, 512);

  // 2) QKV GEMM: [65536,512] x [512,1536] -> [65536,1536] bf16
  dim3 g1(12, 512);
  gemm_bt_kernel<u16><<<g1, 256, 0, stream>>>(x_bf, wqkv_t, qkv_bf, 1536);

  // 3) temporal attention: 2048 (b,s) x 2 head-groups, 256 threads
  attn_mfma_kernel<<<4096, 256, 0, stream>>>(qkv_bf, attn_o);

  // 4) out projection: [65536,512] x [512,512] -> [65536,512] fp32
  dim3 g2(4, 512);
  gemm_bt_kernel<float><<<g2, 256, 0, stream>>>(attn_o, wout_t, outp, 512);
}

// Round 4
// 302.143 us; speedup vs baseline: 1.8734x; 1.1494x over previous
//
#include <hip/hip_runtime.h>
#include <cstdint>
#include <cstddef>

// Problem constants: B=2, T=32, S=1024, D=512, H=8, hd=64, inner=512
#define KDIM 512

typedef __attribute__((ext_vector_type(8))) __bf16 bf16x8;
typedef __attribute__((ext_vector_type(8))) unsigned short ushort8;
typedef __attribute__((ext_vector_type(4))) float f32x4;
typedef unsigned short u16;

__device__ __forceinline__ float bf2f(u16 u) {
  union { unsigned u32; float f; } x; x.u32 = ((unsigned)u) << 16; return x.f;
}
__device__ __forceinline__ u16 f2bf(float f) {
  union { float f; unsigned u; } x; x.f = f;
  unsigned u = x.u;
  unsigned r = (u + 0x7fffu + ((u >> 16) & 1u)) >> 16;
  return (u16)r;
}

// ---------------- cast x (fp32 -> bf16), vectorized float4 ----------------
__global__ __launch_bounds__(256) void cast_x_kernel(const float* __restrict__ in,
                                                     u16* __restrict__ out, int n4) {
  int i = blockIdx.x * 256 + threadIdx.x;
  if (i >= n4) return;
  float4 v = ((const float4*)in)[i];
  ushort4 o;
  o.x = f2bf(v.x); o.y = f2bf(v.y); o.z = f2bf(v.z); o.w = f2bf(v.w);
  ((ushort4*)out)[i] = o;
}

// ---------------- transpose + cast W: in[R][C] fp32 -> out[C][R] bf16 ------
__global__ __launch_bounds__(256) void transpose_cast_kernel(const float* __restrict__ in,
                                                             u16* __restrict__ out,
                                                             int R, int C) {
  int o = blockIdx.x * 256 + threadIdx.x;
  if (o >= R * C) return;
  int r = o % R;
  int c = o / R;
  out[o] = f2bf(in[(size_t)r * C + c]);
}

__device__ __forceinline__ void gload_lds16(const void* g, void* l) {
  __builtin_amdgcn_global_load_lds((__attribute__((address_space(1))) unsigned int*)g,
                                   (__attribute__((address_space(3))) unsigned int*)l,
                                   16, 0, 0);
}

// ---------------- 256x256 counted-vmcnt GEMM: C = A[M][512] * Bt[N][512]^T --
// 512 threads = 8 waves (2M x 4N); per-wave 128x64 output, acc[8][4].
// LDS 128 KiB: double-buffered 256x64 bf16 A and B tiles.
// T2: linear LDS dest + pre-swizzled global SOURCE + XOR on read (row&7).
// T4: depth-2 prefetch, vmcnt(8) at loop head (1 tile in flight), drain 0 only
//     in the peeled last iteration. Raw s_barrier (no implicit vmcnt-0 drain).
// T5: setprio around MFMA clusters.  T1: bijective XCD swizzle (nwg % 8 == 0).
template <typename OutT>
__global__ __launch_bounds__(512, 2) void gemm256_kernel(const u16* __restrict__ A,
                                                         const u16* __restrict__ Bt,
                                                         OutT* __restrict__ C,
                                                         int N, int NXT) {
  __shared__ __attribute__((aligned(16))) u16 As[2][256 * 64];
  __shared__ __attribute__((aligned(16))) u16 Bs[2][256 * 64];
  const int tid = threadIdx.x;
  const int wid = tid >> 6, l = tid & 63;
  const int wm = wid >> 2, wn = wid & 3;
  const int g = l >> 4, i = l & 15;

  // T1: XCD-aware swizzle of the flat block index (nwg divisible by 8)
  const int nwg = gridDim.x;
  const int cpx = nwg >> 3;
  const int bid = blockIdx.x;
  const int swz = (bid & 7) * cpx + (bid >> 3);
  const int mt = swz / NXT, nt = swz % NXT;
  const size_t m0 = (size_t)mt * 256, n0 = (size_t)nt * 256;

  // staging: chunk = 1 KiB = 8 rows x 64 cols; lane l writes phys l*16 B.
  // phys row-in-chunk = l>>3, phys 16B-blk = l&7; logical blk = (l&7)^(row&7).
  const int srow = l >> 3;
  const int sblk = (l & 7) ^ srow;

  f32x4 acc[8][4] = {};

  auto STAGE = [&](int buf, int t) {
    const int k0 = t << 6;
#pragma unroll
    for (int j = 0; j < 4; ++j) {
      int c = wid * 4 + j;
      gload_lds16(A + (m0 + c * 8 + srow) * KDIM + k0 + sblk * 8, &As[buf][c * 512]);
    }
#pragma unroll
    for (int j = 0; j < 4; ++j) {
      int c = wid * 4 + j;
      gload_lds16(Bt + (n0 + c * 8 + srow) * KDIM + k0 + sblk * 8, &Bs[buf][c * 512]);
    }
  };

  auto COMPUTE = [&](int buf) {
#pragma unroll
    for (int ks = 0; ks < 2; ++ks) {
      const int sw = ((ks * 4 + g) ^ (i & 7)) * 8;   // read-side XOR swizzle
      bf16x8 af[8], bv[4];
#pragma unroll
      for (int m = 0; m < 8; ++m)
        af[m] = *(const bf16x8*)&As[buf][(wm * 128 + m * 16 + i) * 64 + sw];
#pragma unroll
      for (int n = 0; n < 4; ++n)
        bv[n] = *(const bf16x8*)&Bs[buf][(wn * 64 + n * 16 + i) * 64 + sw];
      __builtin_amdgcn_s_setprio(1);
#pragma unroll
      for (int m = 0; m < 8; ++m)
#pragma unroll
        for (int n = 0; n < 4; ++n)
          acc[m][n] = __builtin_amdgcn_mfma_f32_16x16x32_bf16(af[m], bv[n], acc[m][n], 0, 0, 0);
      __builtin_amdgcn_s_setprio(0);
    }
  };

  STAGE(0, 0);
  STAGE(1, 1);
  // K = 512 -> 8 tiles of BK=64; last iteration peeled (vmcnt 0, no prefetch)
  for (int t = 0; t < 7; ++t) {
    asm volatile("s_waitcnt vmcnt(8)" ::: "memory");  // tile t landed (mine)
    __builtin_amdgcn_s_barrier();                     // -> everyone's landed
    __builtin_amdgcn_sched_barrier(0);
    COMPUTE(t & 1);
    __builtin_amdgcn_sched_barrier(0);
    __builtin_amdgcn_s_barrier();                     // buf[t&1] reads done
    __builtin_amdgcn_sched_barrier(0);
    if (t < 6) STAGE(t & 1, t + 2);
  }
  asm volatile("s_waitcnt vmcnt(0)" ::: "memory");
  __builtin_amdgcn_s_barrier();
  __builtin_amdgcn_sched_barrier(0);
  COMPUTE(1);

  // epilogue: D row = m*16 + g*4 + r (M side), col = n*16 + i (N side)
#pragma unroll
  for (int m = 0; m < 8; ++m) {
    size_t rowb = m0 + wm * 128 + m * 16 + g * 4;
#pragma unroll
    for (int n = 0; n < 4; ++n) {
      size_t colg = n0 + wn * 64 + n * 16 + i;
#pragma unroll
      for (int r = 0; r < 4; ++r) {
        size_t idx = (rowb + r) * (size_t)N + colg;
        if constexpr (sizeof(OutT) == 2) C[idx] = (OutT)f2bf(acc[m][n][r]);
        else C[idx] = acc[m][n][r];
      }
    }
  }
}

// ---------------- MFMA temporal attention ----------------------------------
// Block = (b, s, head-group of 4). 256 threads = 4 waves, wave = one head.
__global__ __launch_bounds__(256, 4) void attn_mfma_kernel(const u16* __restrict__ qkv,
                                                           u16* __restrict__ out) {
  const int bs = blockIdx.x >> 1;
  const int hg = blockIdx.x & 1;
  const int b = bs >> 10, s = bs & 1023;
  __shared__ __attribute__((aligned(16))) u16 Ks[4][2048];
  __shared__ __attribute__((aligned(16))) u16 Vt[4][2048];
  __shared__ __attribute__((aligned(16))) u16 Ps[4][1024];

  const int tid = threadIdx.x;
  const int wv = tid >> 6;
  const int h = hg * 4 + wv;
  const int l = tid & 63;
  const int g = l >> 4, i = l & 15;

  const size_t tstride = (size_t)1024 * 1536;
  const size_t base = ((size_t)(b * 32) * 1024 + s) * 1536;

  {
    const int krow = l >> 3;
    const int dbs = (l & 7) ^ krow;
#pragma unroll
    for (int j = 0; j < 4; ++j) {
      int k = j * 8 + krow;
      gload_lds16(qkv + base + (size_t)k * tstride + 512 + h * 64 + dbs * 8, &Ks[wv][j * 512]);
    }
  }

  const int vk = l & 31;
  ushort8 vv[4];
#pragma unroll
  for (int j = 0; j < 4; ++j) {
    int c = (l >> 5) + 2 * j;
    vv[j] = *(const ushort8*)(qkv + base + (size_t)vk * tstride + 1024 + h * 64 + c * 8);
  }

  bf16x8 bq[2][2];
#pragma unroll
  for (int n = 0; n < 2; ++n)
#pragma unroll
    for (int ks = 0; ks < 2; ++ks)
      bq[n][ks] = *(const bf16x8*)(qkv + base + (size_t)(n * 16 + i) * tstride + h * 64 + ks * 32 + g * 8);

#pragma unroll
  for (int j = 0; j < 4; ++j) {
    int c = (l >> 5) + 2 * j;
#pragma unroll
    for (int u = 0; u < 8; ++u) {
      int d = c * 8 + u;
      int pos = (vk >> 3) ^ (d & 3);
      Vt[wv][d * 32 + pos * 8 + (vk & 7)] = vv[j][u];
    }
  }

  asm volatile("s_waitcnt vmcnt(0)" ::: "memory");

  f32x4 sc[2][2] = {};
#pragma unroll
  for (int m = 0; m < 2; ++m)
#pragma unroll
    for (int ks = 0; ks < 2; ++ks) {
      int k = m * 16 + i;
      int pos = (ks * 4 + g) ^ (k & 7);
      bf16x8 ak = *(const bf16x8*)&Ks[wv][k * 64 + pos * 8];
      sc[m][0] = __builtin_amdgcn_mfma_f32_16x16x32_bf16(ak, bq[0][ks], sc[m][0], 0, 0, 0);
      sc[m][1] = __builtin_amdgcn_mfma_f32_16x16x32_bf16(ak, bq[1][ks], sc[m][1], 0, 0, 0);
    }

  float p[2][2][4];
#pragma unroll
  for (int n = 0; n < 2; ++n) {
    int q = n * 16 + i;
    float m0 = -1e30f;
#pragma unroll
    for (int m = 0; m < 2; ++m)
#pragma unroll
      for (int r = 0; r < 4; ++r) {
        int k = m * 16 + g * 4 + r;
        float v = (k <= q) ? sc[m][n][r] * 0.125f : -1e30f;
        p[m][n][r] = v;
        m0 = fmaxf(m0, v);
      }
    m0 = fmaxf(m0, __shfl_xor(m0, 16));
    m0 = fmaxf(m0, __shfl_xor(m0, 32));
    float s0 = 0.f;
#pragma unroll
    for (int m = 0; m < 2; ++m)
#pragma unroll
      for (int r = 0; r < 4; ++r) {
        float e = __expf(p[m][n][r] - m0);
        p[m][n][r] = e;
        s0 += e;
      }
    s0 += __shfl_xor(s0, 16);
    s0 += __shfl_xor(s0, 32);
    float inv = 1.f / s0;
#pragma unroll
    for (int m = 0; m < 2; ++m)
#pragma unroll
      for (int r = 0; r < 4; ++r) p[m][n][r] *= inv;
  }

#pragma unroll
  for (int m = 0; m < 2; ++m)
#pragma unroll
    for (int n = 0; n < 2; ++n) {
      int q = n * 16 + i;
      int kb = m * 2 + (g >> 1);
      int pos = kb ^ (q & 3);
      uint2 wo;
      wo.x = (unsigned)f2bf(p[m][n][0]) | ((unsigned)f2bf(p[m][n][1]) << 16);
      wo.y = (unsigned)f2bf(p[m][n][2]) | ((unsigned)f2bf(p[m][n][3]) << 16);
      *(uint2*)&Ps[wv][q * 32 + pos * 8 + (g & 1) * 4] = wo;
    }

  asm volatile("s_waitcnt lgkmcnt(0)" ::: "memory");

  bf16x8 bv[4];
#pragma unroll
  for (int np = 0; np < 4; ++np) {
    int d = np * 16 + i;
    int pos = g ^ (d & 3);
    bv[np] = *(const bf16x8*)&Vt[wv][d * 32 + pos * 8];
  }
  f32x4 o[2][4] = {};
#pragma unroll
  for (int mp = 0; mp < 2; ++mp) {
    int q = mp * 16 + i;
    int pos = g ^ (q & 3);
    bf16x8 ap = *(const bf16x8*)&Ps[wv][q * 32 + pos * 8];
#pragma unroll
    for (int np = 0; np < 4; ++np)
      o[mp][np] = __builtin_amdgcn_mfma_f32_16x16x32_bf16(ap, bv[np], o[mp][np], 0, 0, 0);
  }

#pragma unroll
  for (int mp = 0; mp < 2; ++mp)
#pragma unroll
    for (int r = 0; r < 4; ++r) {
      int q = mp * 16 + g * 4 + r;
      u16* dst = out + ((size_t)((b * 32 + q) * 1024 + s)) * 512 + h * 64;
#pragma unroll
      for (int np = 0; np < 4; ++np)
        dst[np * 16 + i] = f2bf(o[mp][np][r]);
    }
}

// ---------------------------------------------------------------------------
extern "C" void kernel_launch(void* const* d_in, const int* in_sizes, int n_in,
                              void* d_out, int out_size, void* d_ws, size_t ws_size,
                              hipStream_t stream) {
  const float* x = (const float*)d_in[0];     // [2,32,1024,512] fp32
  const float* Wqkv = (const float*)d_in[1];  // [512,1536] fp32
  const float* Wout = (const float*)d_in[2];  // [512,512] fp32
  float* outp = (float*)d_out;                // [2,32,1024,512] fp32

  char* ws = (char*)d_ws;
  u16* x_bf = (u16*)(ws);
  u16* qkv_bf = (u16*)(ws + (size_t)67108864);
  u16* wqkv_t = (u16*)(ws + (size_t)268435456);
  u16* wout_t = (u16*)(ws + (size_t)270008320);
  u16* attn_o = x_bf;  // alias: x_bf16 dead after GEMM1

  // 1) casts
  cast_x_kernel<<<32768, 256, 0, stream>>>(x, x_bf, 8388608);
  transpose_cast_kernel<<<3072, 256, 0, stream>>>(Wqkv, wqkv_t, 512, 1536);
  transpose_cast_kernel<<<1024, 256, 0, stream>>>(Wout, wout_t, 512, 512);

  // 2) QKV GEMM: [65536,512] x [512,1536] -> [65536,1536] bf16
  //    grid = 256 M-tiles x 6 N-tiles = 1536 (divisible by 8 for T1)
  gemm256_kernel<u16><<<1536, 512, 0, stream>>>(x_bf, wqkv_t, qkv_bf, 1536, 6);

  // 3) temporal attention: 2048 (b,s) x 2 head-groups
  attn_mfma_kernel<<<4096, 256, 0, stream>>>(qkv_bf, attn_o);

  // 4) out projection: [65536,512] x [512,512] -> [65536,512] fp32
  //    grid = 256 x 2 = 512 (divisible by 8)
  gemm256_kernel<float><<<512, 512, 0, stream>>>(attn_o, wout_t, outp, 512, 2);
}